// Round 8
// baseline (1639.907 us; speedup 1.0000x reference)
//
#include <hip/hip_runtime.h>

// PolicyNetGARCH: B=1024 S=512 OBS=5 NINS=2 H=32 NBLK=4
// Round 8: R4's proven no-spill skeleton (single loop, barrier at loop top,
// predicated roles) with 2 LSTM blocks per wave, 2 waves per WG.
//   wave 0 = input proj + blocks 0,1 ; wave 1 = blocks 2,3 + head.
// Super-tick = 2 timesteps; pipeline skew 1 super-tick between waves; xt
// pairs handed wave0->wave1 via parity-double-buffered LDS slot.
// NO role-divergent barriers (round 6/7 spilled 8MB..800MB of scratch
// because __syncthreads inside a divergent role branch forces live ranges
// to memory). Weights: 128 VGPRs/wave as packed f16 pairs, exp2-prescaled
// (log2e; 2*log2e for tanh rows) so activations are raw v_exp_f32.
// Cross-lane: DPP reduce, quad_perm pack, permlane32_swap, readlane->SGPR.

constexpr int B_ = 1024, S_ = 512, OBS_ = 5, NINS_ = 2, H_ = 32, NBLK_ = 4;
constexpr int TT_ = S_ / 2;   // super-ticks (2 timesteps each)
constexpr float EPS_ = 1e-6f;
constexpr float LOG2E_ = 1.4426950408889634f;

typedef __fp16 half2_t __attribute__((ext_vector_type(2)));

__device__ __forceinline__ float rcp_(float x) { return __builtin_amdgcn_rcpf(x); }
__device__ __forceinline__ float rsq_(float x) { return __builtin_amdgcn_rsqf(x); }
__device__ __forceinline__ float ex2_(float x) { return __builtin_amdgcn_exp2f(x); }

__device__ __forceinline__ float dot2_(half2_t a, half2_t b, float c) {
  return __builtin_amdgcn_fdot2(a, b, c, false);
}
__device__ __forceinline__ half2_t pk_(float a, float b) {
  return __builtin_amdgcn_cvt_pkrtz(a, b);
}

template <int CTRL>
__device__ __forceinline__ float dppadd_(float v) {
  int m = __builtin_amdgcn_update_dpp(0, __builtin_bit_cast(int, v),
                                      CTRL, 0xF, 0xF, true);
  return v + __builtin_bit_cast(float, m);
}

// Sum over lanes 0..31 (low half), SGPR-broadcast to all lanes.
__device__ __forceinline__ float half_reduce_bcast_(float v) {
  v = dppadd_<0x111>(v);  // row_shr:1
  v = dppadd_<0x112>(v);  // row_shr:2
  v = dppadd_<0x114>(v);  // row_shr:4
  v = dppadd_<0x118>(v);  // row_shr:8  (lane15=sum(0..15), lane31=sum(16..31))
  v = dppadd_<0x142>(v);  // row_bcast:15 -> lane31 = sum(0..31)
  int s = __builtin_amdgcn_readlane(__builtin_bit_cast(int, v), 31);
  return __builtin_bit_cast(float, s);
}

__device__ __forceinline__ float rinv_of_(float xt) {
  const float ms = half_reduce_bcast_(xt * xt);
  return rsq_(ms * (1.0f / 32.0f) + EPS_);
}

// Value held by lane^32, valid in LOW lanes.
__device__ __forceinline__ float swap32_low_(float v) {
#if __has_builtin(__builtin_amdgcn_permlane32_swap)
  auto r = __builtin_amdgcn_permlane32_swap(
      __builtin_bit_cast(int, v), __builtin_bit_cast(int, v), false, false);
  return __builtin_bit_cast(float, (int)r[1]);
#else
  return __shfl_xor(v, 32);
#endif
}

// quad_perm(1,0,3,2): lane^1 exchange.
__device__ __forceinline__ float pairswap_(float v) {
  int m = __builtin_amdgcn_update_dpp(0, __builtin_bit_cast(int, v),
                                      0xB1, 0xF, 0xF, true);
  return __builtin_bit_cast(float, m);
}

// pack low-half 32-vector into 16 SGPR f16-pairs (broadcast)
__device__ __forceinline__ void bcast16_(float y, int (&s)[16]) {
  const half2_t p = pk_(y, pairswap_(y));  // valid at even low lanes
  const int pi = __builtin_bit_cast(int, p);
#pragma unroll
  for (int u = 0; u < 16; ++u) s[u] = __builtin_amdgcn_readlane(pi, 2 * u);
}

// One LSTM block step. xt valid in low lanes; returns h_new (low lanes);
// updates cc and the packed h state.
__device__ __forceinline__ float lstm_block_(
    float xt, const half2_t (&w0)[32], const half2_t (&w1)[32],
    float bias0, float bias1, float rw,
    float& cc, int (&s_h)[16], float aC, float dC) {
  int s_x[16];
  bcast16_(xt * rw, s_x);
  const float rinv = rinv_of_(xt);   // off the broadcast critical path

  float a0x = 0.f, a1x = 0.f, a0xb = 0.f, a1xb = 0.f;
#pragma unroll
  for (int u = 0; u < 16; u += 2) {
    half2_t h0 = __builtin_bit_cast(half2_t, s_x[u]);
    half2_t h1 = __builtin_bit_cast(half2_t, s_x[u + 1]);
    a0x  = dot2_(h0, w0[u],     a0x);
    a1x  = dot2_(h0, w1[u],     a1x);
    a0xb = dot2_(h1, w0[u + 1], a0xb);
    a1xb = dot2_(h1, w1[u + 1], a1xb);
  }
  float a0h = bias0, a1h = bias1, a0hb = 0.f, a1hb = 0.f;
#pragma unroll
  for (int u = 0; u < 16; u += 2) {
    half2_t h0 = __builtin_bit_cast(half2_t, s_h[u]);
    half2_t h1 = __builtin_bit_cast(half2_t, s_h[u + 1]);
    a0h  = dot2_(h0, w0[16 + u], a0h);
    a1h  = dot2_(h0, w1[16 + u], a1h);
    a0hb = dot2_(h1, w0[17 + u], a0hb);
    a1hb = dot2_(h1, w1[17 + u], a1hb);
  }
  const float a0 = fmaf(rinv, a0x + a0xb, a0h + a0hb);  // log2e-scaled gates
  const float a1 = fmaf(rinv, a1x + a1xb, a1h + a1hb);

  // low lane: a0=i, a1=g ; high lane: a0=f, a1=o   (exp2 domain)
  const float g0 = rcp_(1.0f + ex2_(-a0));
  const float g1 = fmaf(aC, rcp_(1.0f + ex2_(-a1)), dC);
  const float x0 = swap32_low_(g0);  // low: sig(f)
  const float x1 = swap32_low_(g1);  // low: sig(o)
  cc = x0 * cc + g0 * g1;
  const float tc = fmaf(2.f, rcp_(1.0f + ex2_(-2.f * LOG2E_ * cc)), -1.f);
  const float hn = x1 * tc;
  bcast16_(hn, s_h);
  return hn;
}

__global__ __launch_bounds__(128, 2) void garch_skew2_kernel(
    const float* __restrict__ obs, const float* __restrict__ prev,
    const float* __restrict__ W_in, const float* __restrict__ b_in,
    const float* __restrict__ rms_w,
    const float* __restrict__ W_ih, const float* __restrict__ W_hh,
    const float* __restrict__ b_ih, const float* __restrict__ b_hh,
    const float* __restrict__ head_w, const float* __restrict__ head_b,
    float* __restrict__ out) {
  const int b    = blockIdx.x;
  const int tid  = threadIdx.x;
  const int k    = tid >> 6;          // wave role: 0 or 1 (R4 pattern)
  const int lane = tid & 63;
  const int hl   = lane & 31;
  const bool low = (lane < 32);

  __shared__ float slot[2][2][H_];    // [parity][step][h]

  const float aC = low ?  2.f : 1.f;
  const float dC = low ? -1.f : 0.f;
  const float s1 = low ? 2.f * LOG2E_ : LOG2E_;

  // ---- weights for this wave's 2 blocks (kg = 2k+j) ----
  half2_t w0[2][32], w1[2][32];
  float bias0[2], bias1[2], rwv[2];
#pragma unroll
  for (int j = 0; j < 2; ++j) {
    const int kg = 2 * k + j;
    const float2* Wih0 = (const float2*)(W_ih + (size_t)kg * 128 * 32 + (size_t)lane * 32);
    const float2* Wih1 = (const float2*)(W_ih + (size_t)kg * 128 * 32 + (size_t)(lane + 64) * 32);
    const float2* Whh0 = (const float2*)(W_hh + (size_t)kg * 128 * 32 + (size_t)lane * 32);
    const float2* Whh1 = (const float2*)(W_hh + (size_t)kg * 128 * 32 + (size_t)(lane + 64) * 32);
#pragma unroll
    for (int t = 0; t < 16; ++t) {
      float2 a = Wih0[t], c2 = Whh0[t], d2 = Wih1[t], e2 = Whh1[t];
      w0[j][t]      = pk_(a.x * LOG2E_,  a.y * LOG2E_);
      w0[j][16 + t] = pk_(c2.x * LOG2E_, c2.y * LOG2E_);
      w1[j][t]      = pk_(d2.x * s1,     d2.y * s1);
      w1[j][16 + t] = pk_(e2.x * s1,     e2.y * s1);
    }
    bias0[j] = (b_ih[kg * 128 + lane]      + b_hh[kg * 128 + lane])      * LOG2E_;
    bias1[j] = (b_ih[kg * 128 + lane + 64] + b_hh[kg * 128 + lane + 64]) * s1;
    rwv[j]   = rms_w[kg * 32 + hl];
  }

  // role-specific constants (small predicated sections, as in R4)
  float win[7]; float bi = 0.f;
  float hw0 = 0.f, hw1 = 0.f, hb0 = 0.f, hb1 = 0.f;
  if (k == 0) {
#pragma unroll
    for (int j = 0; j < 7; ++j) win[j] = W_in[hl * 7 + j];
    bi = b_in[hl];
  } else {
    hw0 = head_w[hl]      * LOG2E_;
    hw1 = head_w[32 + hl] * LOG2E_;
    hb0 = head_b[0] * LOG2E_;
    hb1 = head_b[1] * LOG2E_;
  }

  float cc[2] = {0.f, 0.f};
  int s_h[2][16];
#pragma unroll
  for (int j = 0; j < 2; ++j)
#pragma unroll
    for (int u = 0; u < 16; ++u) s_h[j][u] = 0;

  const float* obs_b  = obs  + (size_t)b * S_ * OBS_;
  const float* prev_b = prev + (size_t)b * S_ * NINS_;
  float incur[14], innx[14];   // timestep-pair inputs (A: 0..6, B: 7..13)
  if (k == 0) {
#pragma unroll
    for (int j = 0; j < 5; ++j) { incur[j] = obs_b[j]; incur[7 + j] = obs_b[5 + j]; }
    incur[5]  = prev_b[0]; incur[6]  = prev_b[1];
    incur[12] = prev_b[2]; incur[13] = prev_b[3];
  }

  float* out_y  = out;                                   // [2][B][S]
  float* out_hT = out + (size_t)NINS_ * B_ * S_;         // [4][B][H]
  float* out_cT = out_hT + (size_t)NBLK_ * B_ * H_;      // [4][B][H]

  for (int tau = 0; tau < TT_ + 1; ++tau) {
    __syncthreads();                 // every thread, every super-tick
    const int tt = tau - k;          // wave-uniform window
    if (tt < 0 || tt >= TT_) continue;
    const int t0 = 2 * tt;

    if (k == 0) {
      // ---- producer: input proj + blocks 0,1 for steps t0, t0+1 ----
      float xtA = bi, xtB = bi;
#pragma unroll
      for (int j = 0; j < 7; ++j) {
        xtA = fmaf(win[j], incur[j],     xtA);
        xtB = fmaf(win[j], incur[7 + j], xtB);
      }
      if (tt + 1 < TT_) {            // prefetch next pair (off-chain)
        const float* o2 = obs_b  + (size_t)(t0 + 2) * OBS_;
        const float* p2 = prev_b + (size_t)(t0 + 2) * NINS_;
#pragma unroll
        for (int j = 0; j < 5; ++j) { innx[j] = o2[j]; innx[7 + j] = o2[5 + j]; }
        innx[5]  = p2[0]; innx[6]  = p2[1];
        innx[12] = p2[2]; innx[13] = p2[3];
      }

      xtA += lstm_block_(xtA, w0[0], w1[0], bias0[0], bias1[0], rwv[0], cc[0], s_h[0], aC, dC);
      const float hA1 = lstm_block_(xtA, w0[1], w1[1], bias0[1], bias1[1], rwv[1], cc[1], s_h[1], aC, dC);
      xtA += hA1;
      xtB += lstm_block_(xtB, w0[0], w1[0], bias0[0], bias1[0], rwv[0], cc[0], s_h[0], aC, dC);
      const float hB1 = lstm_block_(xtB, w0[1], w1[1], bias0[1], bias1[1], rwv[1], cc[1], s_h[1], aC, dC);
      xtB += hB1;

      if (low) {
        slot[tau & 1][0][hl] = xtA;
        slot[tau & 1][1][hl] = xtB;
      }
      if (tt == TT_ - 1 && low) {
        const half2_t h0v = __builtin_bit_cast(half2_t, s_h[0][hl >> 1]);
        out_hT[((size_t)0 * B_ + b) * H_ + hl] = (float)h0v[hl & 1];
        out_hT[((size_t)1 * B_ + b) * H_ + hl] = hB1;
        out_cT[((size_t)0 * B_ + b) * H_ + hl] = cc[0];
        out_cT[((size_t)1 * B_ + b) * H_ + hl] = cc[1];
      }
#pragma unroll
      for (int j = 0; j < 14; ++j) incur[j] = innx[j];
    } else {
      // ---- consumer: blocks 2,3 + head for steps t0, t0+1 ----
      float xtA = slot[tt & 1][0][hl];
      float xtB = slot[tt & 1][1][hl];

      xtA += lstm_block_(xtA, w0[0], w1[0], bias0[0], bias1[0], rwv[0], cc[0], s_h[0], aC, dC);
      const float hA3 = lstm_block_(xtA, w0[1], w1[1], bias0[1], bias1[1], rwv[1], cc[1], s_h[1], aC, dC);
      xtA += hA3;
      const float p0A = half_reduce_bcast_(xtA * hw0) + hb0;
      const float p1A = half_reduce_bcast_(xtA * hw1) + hb1;

      xtB += lstm_block_(xtB, w0[0], w1[0], bias0[0], bias1[0], rwv[0], cc[0], s_h[0], aC, dC);
      const float hB3 = lstm_block_(xtB, w0[1], w1[1], bias0[1], bias1[1], rwv[1], cc[1], s_h[1], aC, dC);
      xtB += hB3;
      const float p0B = half_reduce_bcast_(xtB * hw0) + hb0;
      const float p1B = half_reduce_bcast_(xtB * hw1) + hb1;

      if (lane == 0) {
        const float v0A = copysignf(fminf(ex2_(fabsf(p0A)) - 1.0f, 5.0f),  p0A);
        const float v0B = copysignf(fminf(ex2_(fabsf(p0B)) - 1.0f, 5.0f),  p0B);
        const float v1A = copysignf(fminf(ex2_(fabsf(p1A)) - 1.0f, 10.0f), p1A);
        const float v1B = copysignf(fminf(ex2_(fabsf(p1B)) - 1.0f, 10.0f), p1B);
        *(float2*)&out_y[(size_t)b * S_ + t0]                   = make_float2(v0A, v0B);
        *(float2*)&out_y[(size_t)B_ * S_ + (size_t)b * S_ + t0] = make_float2(v1A, v1B);
      }
      if (tt == TT_ - 1 && low) {
        const half2_t h2v = __builtin_bit_cast(half2_t, s_h[0][hl >> 1]);
        out_hT[((size_t)2 * B_ + b) * H_ + hl] = (float)h2v[hl & 1];
        out_hT[((size_t)3 * B_ + b) * H_ + hl] = hB3;
        out_cT[((size_t)2 * B_ + b) * H_ + hl] = cc[0];
        out_cT[((size_t)3 * B_ + b) * H_ + hl] = cc[1];
      }
    }
  }
}

extern "C" void kernel_launch(void* const* d_in, const int* in_sizes, int n_in,
                              void* d_out, int out_size, void* d_ws, size_t ws_size,
                              hipStream_t stream) {
  (void)in_sizes; (void)n_in; (void)d_ws; (void)ws_size; (void)out_size;
  garch_skew2_kernel<<<dim3(B_), dim3(128), 0, stream>>>(
      (const float*)d_in[0],  // obs_sequence [B,S,OBS]
      (const float*)d_in[1],  // prev_actions [B,S,NINS]
      (const float*)d_in[2],  // W_in [H, OBS+NINS]
      (const float*)d_in[3],  // b_in [H]
      (const float*)d_in[4],  // rms_w [NBLK,H]
      (const float*)d_in[5],  // W_ih [NBLK,4H,H]
      (const float*)d_in[6],  // W_hh [NBLK,4H,H]
      (const float*)d_in[7],  // b_ih [NBLK,4H]
      (const float*)d_in[8],  // b_hh [NBLK,4H]
      (const float*)d_in[9],  // head_w [NINS,H]
      (const float*)d_in[10], // head_b [NINS]
      (float*)d_out);
}

// Round 9
// 829.613 us; speedup vs baseline: 1.9767x; 1.9767x over previous
//
#include <hip/hip_runtime.h>

// PolicyNetGARCH: B=1024 S=512 OBS=5 NINS=2 H=32 NBLK=4
// Round 9: R8's structure (2 waves/WG, 2 LSTM blocks per wave, super-tick =
// 2 timesteps, R4's proven single-loop barrier skeleton) but with the spill
// bug fixed: NO arrays-of-arrays, NO array-reference function params.
// R6/R7/R8 all passed sub-arrays (w0[j], s_h[k]) by reference into an
// inlined helper -> SROA failed -> weight/state arrays lived in scratch
// (R8: 2.3 GB writes/dispatch). Here every array is a flat top-level local
// (w0A/w1A/w0B/w1B, shA/shB) and the block step is a macro, so after
// unrolling every index is a compile-time constant (the R4/R5 pattern that
// allocated cleanly: VGPR 80/156, zero scratch).
//   wave 0 = input proj + blocks 0,1 ; wave 1 = blocks 2,3 + head.
// Gates exp2-prescaled (log2e, 2*log2e for tanh rows) -> raw v_exp_f32.
// Cross-lane: DPP reduce, quad_perm pack, permlane32_swap, readlane->SGPR.

constexpr int B_ = 1024, S_ = 512, OBS_ = 5, NINS_ = 2, H_ = 32, NBLK_ = 4;
constexpr int TT_ = S_ / 2;   // super-ticks (2 timesteps each)
constexpr float EPS_ = 1e-6f;
constexpr float LOG2E_ = 1.4426950408889634f;

typedef __fp16 half2_t __attribute__((ext_vector_type(2)));

__device__ __forceinline__ float rcp_(float x) { return __builtin_amdgcn_rcpf(x); }
__device__ __forceinline__ float rsq_(float x) { return __builtin_amdgcn_rsqf(x); }
__device__ __forceinline__ float ex2_(float x) { return __builtin_amdgcn_exp2f(x); }

__device__ __forceinline__ float dot2_(half2_t a, half2_t b, float c) {
  return __builtin_amdgcn_fdot2(a, b, c, false);
}
__device__ __forceinline__ half2_t pk_(float a, float b) {
  return __builtin_amdgcn_cvt_pkrtz(a, b);
}

template <int CTRL>
__device__ __forceinline__ float dppadd_(float v) {
  int m = __builtin_amdgcn_update_dpp(0, __builtin_bit_cast(int, v),
                                      CTRL, 0xF, 0xF, true);
  return v + __builtin_bit_cast(float, m);
}

// Sum over lanes 0..31 (low half), SGPR-broadcast to all lanes.
__device__ __forceinline__ float half_reduce_bcast_(float v) {
  v = dppadd_<0x111>(v);  // row_shr:1
  v = dppadd_<0x112>(v);  // row_shr:2
  v = dppadd_<0x114>(v);  // row_shr:4
  v = dppadd_<0x118>(v);  // row_shr:8
  v = dppadd_<0x142>(v);  // row_bcast:15 -> lane31 = sum(0..31)
  int s = __builtin_amdgcn_readlane(__builtin_bit_cast(int, v), 31);
  return __builtin_bit_cast(float, s);
}

__device__ __forceinline__ float rinv_of_(float xt) {
  const float ms = half_reduce_bcast_(xt * xt);
  return rsq_(ms * (1.0f / 32.0f) + EPS_);
}

// Value held by lane^32, valid in LOW lanes.
__device__ __forceinline__ float swap32_low_(float v) {
#if __has_builtin(__builtin_amdgcn_permlane32_swap)
  auto r = __builtin_amdgcn_permlane32_swap(
      __builtin_bit_cast(int, v), __builtin_bit_cast(int, v), false, false);
  return __builtin_bit_cast(float, (int)r[1]);
#else
  return __shfl_xor(v, 32);
#endif
}

// quad_perm(1,0,3,2): lane^1 exchange.
__device__ __forceinline__ float pairswap_(float v) {
  int m = __builtin_amdgcn_update_dpp(0, __builtin_bit_cast(int, v),
                                      0xB1, 0xF, 0xF, true);
  return __builtin_bit_cast(float, m);
}

// pack low-half mirrored 32-vector Y into 16 SGPR f16-pairs in flat array S
#define BCAST16(Y, S)                                                     \
  do {                                                                    \
    const float _y = (Y);                                                 \
    const half2_t _p = pk_(_y, pairswap_(_y));                            \
    const int _pi = __builtin_bit_cast(int, _p);                          \
    _Pragma("unroll")                                                     \
    for (int _u = 0; _u < 16; ++_u)                                       \
      S[_u] = __builtin_amdgcn_readlane(_pi, 2 * _u);                     \
  } while (0)

// One LSTM block step on flat arrays. Updates CC, SH; writes h_new to HN.
#define LSTM_STEP(XT, W0A, W1A, BIAS0, BIAS1, RW, CC, SH, HN)             \
  do {                                                                    \
    int _sx[16];                                                          \
    BCAST16((XT) * (RW), _sx);                                            \
    const float _rinv = rinv_of_(XT);                                     \
    float _a0x = 0.f, _a1x = 0.f, _a0xb = 0.f, _a1xb = 0.f;               \
    _Pragma("unroll")                                                     \
    for (int _u = 0; _u < 16; _u += 2) {                                  \
      half2_t _h0 = __builtin_bit_cast(half2_t, _sx[_u]);                 \
      half2_t _h1 = __builtin_bit_cast(half2_t, _sx[_u + 1]);             \
      _a0x  = dot2_(_h0, W0A[_u],     _a0x);                              \
      _a1x  = dot2_(_h0, W1A[_u],     _a1x);                              \
      _a0xb = dot2_(_h1, W0A[_u + 1], _a0xb);                             \
      _a1xb = dot2_(_h1, W1A[_u + 1], _a1xb);                             \
    }                                                                     \
    float _a0h = (BIAS0), _a1h = (BIAS1), _a0hb = 0.f, _a1hb = 0.f;       \
    _Pragma("unroll")                                                     \
    for (int _u = 0; _u < 16; _u += 2) {                                  \
      half2_t _h0 = __builtin_bit_cast(half2_t, SH[_u]);                  \
      half2_t _h1 = __builtin_bit_cast(half2_t, SH[_u + 1]);              \
      _a0h  = dot2_(_h0, W0A[16 + _u], _a0h);                             \
      _a1h  = dot2_(_h0, W1A[16 + _u], _a1h);                             \
      _a0hb = dot2_(_h1, W0A[17 + _u], _a0hb);                            \
      _a1hb = dot2_(_h1, W1A[17 + _u], _a1hb);                            \
    }                                                                     \
    const float _a0 = fmaf(_rinv, _a0x + _a0xb, _a0h + _a0hb);            \
    const float _a1 = fmaf(_rinv, _a1x + _a1xb, _a1h + _a1hb);            \
    const float _g0 = rcp_(1.0f + ex2_(-_a0));                            \
    const float _g1 = fmaf(aC, rcp_(1.0f + ex2_(-_a1)), dC);              \
    const float _x0 = swap32_low_(_g0);                                   \
    const float _x1 = swap32_low_(_g1);                                   \
    (CC) = _x0 * (CC) + _g0 * _g1;                                        \
    const float _tc = fmaf(2.f, rcp_(1.0f + ex2_(-2.f * LOG2E_ * (CC))), -1.f); \
    (HN) = _x1 * _tc;                                                     \
    BCAST16((HN), SH);                                                    \
  } while (0)

__global__ __launch_bounds__(128, 2) void garch_flat_kernel(
    const float* __restrict__ obs, const float* __restrict__ prev,
    const float* __restrict__ W_in, const float* __restrict__ b_in,
    const float* __restrict__ rms_w,
    const float* __restrict__ W_ih, const float* __restrict__ W_hh,
    const float* __restrict__ b_ih, const float* __restrict__ b_hh,
    const float* __restrict__ head_w, const float* __restrict__ head_b,
    float* __restrict__ out) {
  const int b    = blockIdx.x;
  const int tid  = threadIdx.x;
  const int k    = tid >> 6;          // wave role: 0 or 1
  const int lane = tid & 63;
  const int hl   = lane & 31;
  const bool low = (lane < 32);

  __shared__ float slot[2][2][H_];    // [parity][step][h]

  const float aC = low ?  2.f : 1.f;
  const float dC = low ? -1.f : 0.f;
  const float s1 = low ? 2.f * LOG2E_ : LOG2E_;

  // ---- weights: FLAT arrays, block A = 2k, block B = 2k+1 ----
  half2_t w0A[32], w1A[32], w0B[32], w1B[32];
  float bias0A, bias1A, rwA, bias0B, bias1B, rwB;
  {
    const int kg = 2 * k;
    const float2* Wih0 = (const float2*)(W_ih + (size_t)kg * 128 * 32 + (size_t)lane * 32);
    const float2* Wih1 = (const float2*)(W_ih + (size_t)kg * 128 * 32 + (size_t)(lane + 64) * 32);
    const float2* Whh0 = (const float2*)(W_hh + (size_t)kg * 128 * 32 + (size_t)lane * 32);
    const float2* Whh1 = (const float2*)(W_hh + (size_t)kg * 128 * 32 + (size_t)(lane + 64) * 32);
#pragma unroll
    for (int t = 0; t < 16; ++t) {
      float2 a = Wih0[t], c2 = Whh0[t], d2 = Wih1[t], e2 = Whh1[t];
      w0A[t]      = pk_(a.x * LOG2E_,  a.y * LOG2E_);
      w0A[16 + t] = pk_(c2.x * LOG2E_, c2.y * LOG2E_);
      w1A[t]      = pk_(d2.x * s1,     d2.y * s1);
      w1A[16 + t] = pk_(e2.x * s1,     e2.y * s1);
    }
    bias0A = (b_ih[kg * 128 + lane]      + b_hh[kg * 128 + lane])      * LOG2E_;
    bias1A = (b_ih[kg * 128 + lane + 64] + b_hh[kg * 128 + lane + 64]) * s1;
    rwA    = rms_w[kg * 32 + hl];
  }
  {
    const int kg = 2 * k + 1;
    const float2* Wih0 = (const float2*)(W_ih + (size_t)kg * 128 * 32 + (size_t)lane * 32);
    const float2* Wih1 = (const float2*)(W_ih + (size_t)kg * 128 * 32 + (size_t)(lane + 64) * 32);
    const float2* Whh0 = (const float2*)(W_hh + (size_t)kg * 128 * 32 + (size_t)lane * 32);
    const float2* Whh1 = (const float2*)(W_hh + (size_t)kg * 128 * 32 + (size_t)(lane + 64) * 32);
#pragma unroll
    for (int t = 0; t < 16; ++t) {
      float2 a = Wih0[t], c2 = Whh0[t], d2 = Wih1[t], e2 = Whh1[t];
      w0B[t]      = pk_(a.x * LOG2E_,  a.y * LOG2E_);
      w0B[16 + t] = pk_(c2.x * LOG2E_, c2.y * LOG2E_);
      w1B[t]      = pk_(d2.x * s1,     d2.y * s1);
      w1B[16 + t] = pk_(e2.x * s1,     e2.y * s1);
    }
    bias0B = (b_ih[kg * 128 + lane]      + b_hh[kg * 128 + lane])      * LOG2E_;
    bias1B = (b_ih[kg * 128 + lane + 64] + b_hh[kg * 128 + lane + 64]) * s1;
    rwB    = rms_w[kg * 32 + hl];
  }

  // role-specific constants (small predicated sections, R4 pattern)
  float win[7]; float bi = 0.f;
  float hw0 = 0.f, hw1 = 0.f, hb0 = 0.f, hb1 = 0.f;
  if (k == 0) {
#pragma unroll
    for (int j = 0; j < 7; ++j) win[j] = W_in[hl * 7 + j];
    bi = b_in[hl];
  } else {
    hw0 = head_w[hl]      * LOG2E_;
    hw1 = head_w[32 + hl] * LOG2E_;
    hb0 = head_b[0] * LOG2E_;
    hb1 = head_b[1] * LOG2E_;
  }

  float ccA = 0.f, ccB = 0.f;
  int shA[16], shB[16];
#pragma unroll
  for (int u = 0; u < 16; ++u) { shA[u] = 0; shB[u] = 0; }

  const float* obs_b  = obs  + (size_t)b * S_ * OBS_;
  const float* prev_b = prev + (size_t)b * S_ * NINS_;
  float incur[14], innx[14];   // timestep-pair inputs (A: 0..6, B: 7..13)
  if (k == 0) {
#pragma unroll
    for (int j = 0; j < 5; ++j) { incur[j] = obs_b[j]; incur[7 + j] = obs_b[5 + j]; }
    incur[5]  = prev_b[0]; incur[6]  = prev_b[1];
    incur[12] = prev_b[2]; incur[13] = prev_b[3];
  }

  float* out_y  = out;                                   // [2][B][S]
  float* out_hT = out + (size_t)NINS_ * B_ * S_;         // [4][B][H]
  float* out_cT = out_hT + (size_t)NBLK_ * B_ * H_;      // [4][B][H]

  for (int tau = 0; tau < TT_ + 1; ++tau) {
    __syncthreads();                 // every thread, every super-tick
    const int tt = tau - k;          // wave-uniform window
    if (tt < 0 || tt >= TT_) continue;
    const int t0 = 2 * tt;

    if (k == 0) {
      // ---- producer: input proj + blocks 0,1 for steps t0, t0+1 ----
      float xtA = bi, xtB = bi;
#pragma unroll
      for (int j = 0; j < 7; ++j) {
        xtA = fmaf(win[j], incur[j],     xtA);
        xtB = fmaf(win[j], incur[7 + j], xtB);
      }
      if (tt + 1 < TT_) {            // prefetch next pair (off-chain)
        const float* o2 = obs_b  + (size_t)(t0 + 2) * OBS_;
        const float* p2 = prev_b + (size_t)(t0 + 2) * NINS_;
#pragma unroll
        for (int j = 0; j < 5; ++j) { innx[j] = o2[j]; innx[7 + j] = o2[5 + j]; }
        innx[5]  = p2[0]; innx[6]  = p2[1];
        innx[12] = p2[2]; innx[13] = p2[3];
      }

      float hn0, hn1;
      LSTM_STEP(xtA, w0A, w1A, bias0A, bias1A, rwA, ccA, shA, hn0);
      xtA += hn0;
      LSTM_STEP(xtA, w0B, w1B, bias0B, bias1B, rwB, ccB, shB, hn1);
      xtA += hn1;
      LSTM_STEP(xtB, w0A, w1A, bias0A, bias1A, rwA, ccA, shA, hn0);
      xtB += hn0;
      LSTM_STEP(xtB, w0B, w1B, bias0B, bias1B, rwB, ccB, shB, hn1);
      xtB += hn1;

      if (low) {
        slot[tau & 1][0][hl] = xtA;
        slot[tau & 1][1][hl] = xtB;
      }
      if (tt == TT_ - 1 && low) {
        const half2_t h0v = __builtin_bit_cast(half2_t, shA[hl >> 1]);
        out_hT[((size_t)0 * B_ + b) * H_ + hl] = (float)h0v[hl & 1];
        out_hT[((size_t)1 * B_ + b) * H_ + hl] = hn1;
        out_cT[((size_t)0 * B_ + b) * H_ + hl] = ccA;
        out_cT[((size_t)1 * B_ + b) * H_ + hl] = ccB;
      }
#pragma unroll
      for (int j = 0; j < 14; ++j) incur[j] = innx[j];
    } else {
      // ---- consumer: blocks 2,3 + head for steps t0, t0+1 ----
      float xtA = slot[tt & 1][0][hl];
      float xtB = slot[tt & 1][1][hl];

      float hn2, hn3;
      LSTM_STEP(xtA, w0A, w1A, bias0A, bias1A, rwA, ccA, shA, hn2);
      xtA += hn2;
      LSTM_STEP(xtA, w0B, w1B, bias0B, bias1B, rwB, ccB, shB, hn3);
      xtA += hn3;
      const float p0A = half_reduce_bcast_(xtA * hw0) + hb0;
      const float p1A = half_reduce_bcast_(xtA * hw1) + hb1;

      LSTM_STEP(xtB, w0A, w1A, bias0A, bias1A, rwA, ccA, shA, hn2);
      xtB += hn2;
      LSTM_STEP(xtB, w0B, w1B, bias0B, bias1B, rwB, ccB, shB, hn3);
      xtB += hn3;
      const float p0B = half_reduce_bcast_(xtB * hw0) + hb0;
      const float p1B = half_reduce_bcast_(xtB * hw1) + hb1;

      if (lane == 0) {
        const float v0A = copysignf(fminf(ex2_(fabsf(p0A)) - 1.0f, 5.0f),  p0A);
        const float v0B = copysignf(fminf(ex2_(fabsf(p0B)) - 1.0f, 5.0f),  p0B);
        const float v1A = copysignf(fminf(ex2_(fabsf(p1A)) - 1.0f, 10.0f), p1A);
        const float v1B = copysignf(fminf(ex2_(fabsf(p1B)) - 1.0f, 10.0f), p1B);
        *(float2*)&out_y[(size_t)b * S_ + t0]                   = make_float2(v0A, v0B);
        *(float2*)&out_y[(size_t)B_ * S_ + (size_t)b * S_ + t0] = make_float2(v1A, v1B);
      }
      if (tt == TT_ - 1 && low) {
        const half2_t h2v = __builtin_bit_cast(half2_t, shA[hl >> 1]);
        out_hT[((size_t)2 * B_ + b) * H_ + hl] = (float)h2v[hl & 1];
        out_hT[((size_t)3 * B_ + b) * H_ + hl] = hn3;
        out_cT[((size_t)2 * B_ + b) * H_ + hl] = ccA;
        out_cT[((size_t)3 * B_ + b) * H_ + hl] = ccB;
      }
    }
  }
}

extern "C" void kernel_launch(void* const* d_in, const int* in_sizes, int n_in,
                              void* d_out, int out_size, void* d_ws, size_t ws_size,
                              hipStream_t stream) {
  (void)in_sizes; (void)n_in; (void)d_ws; (void)ws_size; (void)out_size;
  garch_flat_kernel<<<dim3(B_), dim3(128), 0, stream>>>(
      (const float*)d_in[0],  // obs_sequence [B,S,OBS]
      (const float*)d_in[1],  // prev_actions [B,S,NINS]
      (const float*)d_in[2],  // W_in [H, OBS+NINS]
      (const float*)d_in[3],  // b_in [H]
      (const float*)d_in[4],  // rms_w [NBLK,H]
      (const float*)d_in[5],  // W_ih [NBLK,4H,H]
      (const float*)d_in[6],  // W_hh [NBLK,4H,H]
      (const float*)d_in[7],  // b_ih [NBLK,4H]
      (const float*)d_in[8],  // b_hh [NBLK,4H]
      (const float*)d_in[9],  // head_w [NINS,H]
      (const float*)d_in[10], // head_b [NINS]
      (float*)d_out);
}

// Round 10
// 773.568 us; speedup vs baseline: 2.1199x; 1.0725x over previous
//
#include <hip/hip_runtime.h>

// PolicyNetGARCH: B=1024 S=512 OBS=5 NINS=2 H=32 NBLK=4
// Round 10: R9 structure (2 waves/WG: wave0 = proj + blocks 0,1; wave1 =
// blocks 2,3 + head; super-tick = 2 timesteps; R4's single-loop barrier
// skeleton) with the promote-alloca bug killed: the SGPR broadcast arrays
// (x and h state) are SIXTEEN NAMED SCALARS (token-pasted), not int[16].
// R9's int[16] got promoted to LDS (8192B extra, 1.1e8 bank conflicts);
// R7/R8's variants spilled to scratch. No alloca -> nothing to demote.
// Weight arrays stay constant-indexed flat locals (R4/R5-proven clean).
// __launch_bounds__(128,1): VGPR cap 512, no occupancy-driven demotion.
// Gates exp2-prescaled (log2e; 2*log2e tanh rows) -> raw v_exp_f32.
// Cross-lane: DPP reduce, quad_perm pack, permlane32_swap, readlane->SGPR.

constexpr int B_ = 1024, S_ = 512, OBS_ = 5, NINS_ = 2, H_ = 32, NBLK_ = 4;
constexpr int TT_ = S_ / 2;   // super-ticks (2 timesteps each)
constexpr float EPS_ = 1e-6f;
constexpr float LOG2E_ = 1.4426950408889634f;

typedef __fp16 half2_t __attribute__((ext_vector_type(2)));

__device__ __forceinline__ float rcp_(float x) { return __builtin_amdgcn_rcpf(x); }
__device__ __forceinline__ float rsq_(float x) { return __builtin_amdgcn_rsqf(x); }
__device__ __forceinline__ float ex2_(float x) { return __builtin_amdgcn_exp2f(x); }

__device__ __forceinline__ float dot2_(half2_t a, half2_t b, float c) {
  return __builtin_amdgcn_fdot2(a, b, c, false);
}
__device__ __forceinline__ half2_t pk_(float a, float b) {
  return __builtin_amdgcn_cvt_pkrtz(a, b);
}

template <int CTRL>
__device__ __forceinline__ float dppadd_(float v) {
  int m = __builtin_amdgcn_update_dpp(0, __builtin_bit_cast(int, v),
                                      CTRL, 0xF, 0xF, true);
  return v + __builtin_bit_cast(float, m);
}

// Sum over lanes 0..31 (low half), SGPR-broadcast to all lanes.
__device__ __forceinline__ float half_reduce_bcast_(float v) {
  v = dppadd_<0x111>(v);  // row_shr:1
  v = dppadd_<0x112>(v);  // row_shr:2
  v = dppadd_<0x114>(v);  // row_shr:4
  v = dppadd_<0x118>(v);  // row_shr:8
  v = dppadd_<0x142>(v);  // row_bcast:15 -> lane31 = sum(0..31)
  int s = __builtin_amdgcn_readlane(__builtin_bit_cast(int, v), 31);
  return __builtin_bit_cast(float, s);
}

__device__ __forceinline__ float rinv_of_(float xt) {
  const float ms = half_reduce_bcast_(xt * xt);
  return rsq_(ms * (1.0f / 32.0f) + EPS_);
}

// Value held by lane^32, valid in LOW lanes.
__device__ __forceinline__ float swap32_low_(float v) {
#if __has_builtin(__builtin_amdgcn_permlane32_swap)
  auto r = __builtin_amdgcn_permlane32_swap(
      __builtin_bit_cast(int, v), __builtin_bit_cast(int, v), false, false);
  return __builtin_bit_cast(float, (int)r[1]);
#else
  return __shfl_xor(v, 32);
#endif
}

// quad_perm(1,0,3,2): lane^1 exchange.
__device__ __forceinline__ float pairswap_(float v) {
  int m = __builtin_amdgcn_update_dpp(0, __builtin_bit_cast(int, v),
                                      0xB1, 0xF, 0xF, true);
  return __builtin_bit_cast(float, m);
}

#define RL_(pi, l) __builtin_amdgcn_readlane((pi), (l))
#define BC_(v)     __builtin_bit_cast(half2_t, (v))

// 16 named ints (no alloca!)
#define DECL16_(P) int P##_0, P##_1, P##_2, P##_3, P##_4, P##_5, P##_6,   \
                       P##_7, P##_8, P##_9, P##_10, P##_11, P##_12,       \
                       P##_13, P##_14, P##_15

// pack mirrored low-half 32-vector Y into 16 named SGPR f16-pairs P_0..P_15
#define BCAST16S_(Y, P) do {                                              \
    const float _yv = (Y);                                                \
    const half2_t _pk2 = pk_(_yv, pairswap_(_yv));                        \
    const int _pi = __builtin_bit_cast(int, _pk2);                        \
    P##_0  = RL_(_pi, 0);  P##_1  = RL_(_pi, 2);                          \
    P##_2  = RL_(_pi, 4);  P##_3  = RL_(_pi, 6);                          \
    P##_4  = RL_(_pi, 8);  P##_5  = RL_(_pi, 10);                         \
    P##_6  = RL_(_pi, 12); P##_7  = RL_(_pi, 14);                         \
    P##_8  = RL_(_pi, 16); P##_9  = RL_(_pi, 18);                         \
    P##_10 = RL_(_pi, 20); P##_11 = RL_(_pi, 22);                         \
    P##_12 = RL_(_pi, 24); P##_13 = RL_(_pi, 26);                         \
    P##_14 = RL_(_pi, 28); P##_15 = RL_(_pi, 30);                         \
  } while (0)

// 16 dual-dot pairs: P_i against W0[OFF+i] -> A0/B0 and W1[OFF+i] -> A1/B1
// (2-way split accumulators for ILP)
#define DOT16_(P, W0, W1, OFF, A0, A1, B0, B1)                            \
    A0 = dot2_(BC_(P##_0),  W0[(OFF) + 0],  A0);                          \
    A1 = dot2_(BC_(P##_0),  W1[(OFF) + 0],  A1);                          \
    B0 = dot2_(BC_(P##_1),  W0[(OFF) + 1],  B0);                          \
    B1 = dot2_(BC_(P##_1),  W1[(OFF) + 1],  B1);                          \
    A0 = dot2_(BC_(P##_2),  W0[(OFF) + 2],  A0);                          \
    A1 = dot2_(BC_(P##_2),  W1[(OFF) + 2],  A1);                          \
    B0 = dot2_(BC_(P##_3),  W0[(OFF) + 3],  B0);                          \
    B1 = dot2_(BC_(P##_3),  W1[(OFF) + 3],  B1);                          \
    A0 = dot2_(BC_(P##_4),  W0[(OFF) + 4],  A0);                          \
    A1 = dot2_(BC_(P##_4),  W1[(OFF) + 4],  A1);                          \
    B0 = dot2_(BC_(P##_5),  W0[(OFF) + 5],  B0);                          \
    B1 = dot2_(BC_(P##_5),  W1[(OFF) + 5],  B1);                          \
    A0 = dot2_(BC_(P##_6),  W0[(OFF) + 6],  A0);                          \
    A1 = dot2_(BC_(P##_6),  W1[(OFF) + 6],  A1);                          \
    B0 = dot2_(BC_(P##_7),  W0[(OFF) + 7],  B0);                          \
    B1 = dot2_(BC_(P##_7),  W1[(OFF) + 7],  B1);                          \
    A0 = dot2_(BC_(P##_8),  W0[(OFF) + 8],  A0);                          \
    A1 = dot2_(BC_(P##_8),  W1[(OFF) + 8],  A1);                          \
    B0 = dot2_(BC_(P##_9),  W0[(OFF) + 9],  B0);                          \
    B1 = dot2_(BC_(P##_9),  W1[(OFF) + 9],  B1);                          \
    A0 = dot2_(BC_(P##_10), W0[(OFF) + 10], A0);                          \
    A1 = dot2_(BC_(P##_10), W1[(OFF) + 10], A1);                          \
    B0 = dot2_(BC_(P##_11), W0[(OFF) + 11], B0);                          \
    B1 = dot2_(BC_(P##_11), W1[(OFF) + 11], B1);                          \
    A0 = dot2_(BC_(P##_12), W0[(OFF) + 12], A0);                          \
    A1 = dot2_(BC_(P##_12), W1[(OFF) + 12], A1);                          \
    B0 = dot2_(BC_(P##_13), W0[(OFF) + 13], B0);                          \
    B1 = dot2_(BC_(P##_13), W1[(OFF) + 13], B1);                          \
    A0 = dot2_(BC_(P##_14), W0[(OFF) + 14], A0);                          \
    A1 = dot2_(BC_(P##_14), W1[(OFF) + 14], A1);                          \
    B0 = dot2_(BC_(P##_15), W0[(OFF) + 15], B0);                          \
    B1 = dot2_(BC_(P##_15), W1[(OFF) + 15], B1)

// One LSTM block step: updates CC and h-state scalars SH_*, writes HN.
#define LSTM_STEP_(XT, W0, W1, BIAS0, BIAS1, RW, CC, SH, HN) do {         \
    DECL16_(sx);                                                          \
    BCAST16S_((XT) * (RW), sx);                                           \
    const float _rinv = rinv_of_(XT);                                     \
    float _x0a = 0.f, _x1a = 0.f, _x0b = 0.f, _x1b = 0.f;                 \
    DOT16_(sx, W0, W1, 0, _x0a, _x1a, _x0b, _x1b);                        \
    float _h0a = (BIAS0), _h1a = (BIAS1), _h0b = 0.f, _h1b = 0.f;         \
    DOT16_(SH, W0, W1, 16, _h0a, _h1a, _h0b, _h1b);                       \
    const float _a0 = fmaf(_rinv, _x0a + _x0b, _h0a + _h0b);              \
    const float _a1 = fmaf(_rinv, _x1a + _x1b, _h1a + _h1b);              \
    const float _g0 = rcp_(1.0f + ex2_(-_a0));                            \
    const float _g1 = fmaf(aC, rcp_(1.0f + ex2_(-_a1)), dC);              \
    const float _s0 = swap32_low_(_g0);                                   \
    const float _s1 = swap32_low_(_g1);                                   \
    (CC) = _s0 * (CC) + _g0 * _g1;                                        \
    const float _tc = fmaf(2.f, rcp_(1.0f + ex2_(-2.f * LOG2E_ * (CC))), -1.f); \
    (HN) = _s1 * _tc;                                                     \
    BCAST16S_((HN), SH);                                                  \
  } while (0)

__global__ __launch_bounds__(128, 1) void garch_noalloca_kernel(
    const float* __restrict__ obs, const float* __restrict__ prev,
    const float* __restrict__ W_in, const float* __restrict__ b_in,
    const float* __restrict__ rms_w,
    const float* __restrict__ W_ih, const float* __restrict__ W_hh,
    const float* __restrict__ b_ih, const float* __restrict__ b_hh,
    const float* __restrict__ head_w, const float* __restrict__ head_b,
    float* __restrict__ out) {
  const int b    = blockIdx.x;
  const int tid  = threadIdx.x;
  const int k    = tid >> 6;          // wave role: 0 or 1
  const int lane = tid & 63;
  const int hl   = lane & 31;
  const bool low = (lane < 32);

  __shared__ float slot[2][2][H_];    // [parity][step][h]

  const float aC = low ?  2.f : 1.f;
  const float dC = low ? -1.f : 0.f;
  const float s1 = low ? 2.f * LOG2E_ : LOG2E_;

  // ---- weights: flat constant-indexed locals; block A = 2k, B = 2k+1 ----
  half2_t w0A[32], w1A[32], w0B[32], w1B[32];
  float bias0A, bias1A, rwA, bias0B, bias1B, rwB;
  {
    const int kg = 2 * k;
    const float2* Wih0 = (const float2*)(W_ih + (size_t)kg * 128 * 32 + (size_t)lane * 32);
    const float2* Wih1 = (const float2*)(W_ih + (size_t)kg * 128 * 32 + (size_t)(lane + 64) * 32);
    const float2* Whh0 = (const float2*)(W_hh + (size_t)kg * 128 * 32 + (size_t)lane * 32);
    const float2* Whh1 = (const float2*)(W_hh + (size_t)kg * 128 * 32 + (size_t)(lane + 64) * 32);
#pragma unroll
    for (int t = 0; t < 16; ++t) {
      float2 a = Wih0[t], c2 = Whh0[t], d2 = Wih1[t], e2 = Whh1[t];
      w0A[t]      = pk_(a.x * LOG2E_,  a.y * LOG2E_);
      w0A[16 + t] = pk_(c2.x * LOG2E_, c2.y * LOG2E_);
      w1A[t]      = pk_(d2.x * s1,     d2.y * s1);
      w1A[16 + t] = pk_(e2.x * s1,     e2.y * s1);
    }
    bias0A = (b_ih[kg * 128 + lane]      + b_hh[kg * 128 + lane])      * LOG2E_;
    bias1A = (b_ih[kg * 128 + lane + 64] + b_hh[kg * 128 + lane + 64]) * s1;
    rwA    = rms_w[kg * 32 + hl];
  }
  {
    const int kg = 2 * k + 1;
    const float2* Wih0 = (const float2*)(W_ih + (size_t)kg * 128 * 32 + (size_t)lane * 32);
    const float2* Wih1 = (const float2*)(W_ih + (size_t)kg * 128 * 32 + (size_t)(lane + 64) * 32);
    const float2* Whh0 = (const float2*)(W_hh + (size_t)kg * 128 * 32 + (size_t)lane * 32);
    const float2* Whh1 = (const float2*)(W_hh + (size_t)kg * 128 * 32 + (size_t)(lane + 64) * 32);
#pragma unroll
    for (int t = 0; t < 16; ++t) {
      float2 a = Wih0[t], c2 = Whh0[t], d2 = Wih1[t], e2 = Whh1[t];
      w0B[t]      = pk_(a.x * LOG2E_,  a.y * LOG2E_);
      w0B[16 + t] = pk_(c2.x * LOG2E_, c2.y * LOG2E_);
      w1B[t]      = pk_(d2.x * s1,     d2.y * s1);
      w1B[16 + t] = pk_(e2.x * s1,     e2.y * s1);
    }
    bias0B = (b_ih[kg * 128 + lane]      + b_hh[kg * 128 + lane])      * LOG2E_;
    bias1B = (b_ih[kg * 128 + lane + 64] + b_hh[kg * 128 + lane + 64]) * s1;
    rwB    = rms_w[kg * 32 + hl];
  }

  // role-specific constants (small predicated sections)
  float win[7]; float bi = 0.f;
  float hw0 = 0.f, hw1 = 0.f, hb0 = 0.f, hb1 = 0.f;
  if (k == 0) {
#pragma unroll
    for (int j = 0; j < 7; ++j) win[j] = W_in[hl * 7 + j];
    bi = b_in[hl];
  } else {
    hw0 = head_w[hl]      * LOG2E_;
    hw1 = head_w[32 + hl] * LOG2E_;
    hb0 = head_b[0] * LOG2E_;
    hb1 = head_b[1] * LOG2E_;
  }

  float ccA = 0.f, ccB = 0.f;
  DECL16_(shA);
  DECL16_(shB);
  shA_0=0;shA_1=0;shA_2=0;shA_3=0;shA_4=0;shA_5=0;shA_6=0;shA_7=0;
  shA_8=0;shA_9=0;shA_10=0;shA_11=0;shA_12=0;shA_13=0;shA_14=0;shA_15=0;
  shB_0=0;shB_1=0;shB_2=0;shB_3=0;shB_4=0;shB_5=0;shB_6=0;shB_7=0;
  shB_8=0;shB_9=0;shB_10=0;shB_11=0;shB_12=0;shB_13=0;shB_14=0;shB_15=0;

  const float* obs_b  = obs  + (size_t)b * S_ * OBS_;
  const float* prev_b = prev + (size_t)b * S_ * NINS_;
  float incur[14], innx[14];   // timestep-pair inputs (A: 0..6, B: 7..13)
  if (k == 0) {
#pragma unroll
    for (int j = 0; j < 5; ++j) { incur[j] = obs_b[j]; incur[7 + j] = obs_b[5 + j]; }
    incur[5]  = prev_b[0]; incur[6]  = prev_b[1];
    incur[12] = prev_b[2]; incur[13] = prev_b[3];
  }

  float* out_y  = out;                                   // [2][B][S]
  float* out_hT = out + (size_t)NINS_ * B_ * S_;         // [4][B][H]
  float* out_cT = out_hT + (size_t)NBLK_ * B_ * H_;      // [4][B][H]

  for (int tau = 0; tau < TT_ + 1; ++tau) {
    __syncthreads();                 // every thread, every super-tick
    const int tt = tau - k;          // wave-uniform window
    if (tt < 0 || tt >= TT_) continue;
    const int t0 = 2 * tt;

    if (k == 0) {
      // ---- producer: input proj + blocks 0,1 for steps t0, t0+1 ----
      float xtA = bi, xtB = bi;
#pragma unroll
      for (int j = 0; j < 7; ++j) {
        xtA = fmaf(win[j], incur[j],     xtA);
        xtB = fmaf(win[j], incur[7 + j], xtB);
      }
      if (tt + 1 < TT_) {            // prefetch next pair (off-chain)
        const float* o2 = obs_b  + (size_t)(t0 + 2) * OBS_;
        const float* p2 = prev_b + (size_t)(t0 + 2) * NINS_;
#pragma unroll
        for (int j = 0; j < 5; ++j) { innx[j] = o2[j]; innx[7 + j] = o2[5 + j]; }
        innx[5]  = p2[0]; innx[6]  = p2[1];
        innx[12] = p2[2]; innx[13] = p2[3];
      }

      float hn0, hn1;
      LSTM_STEP_(xtA, w0A, w1A, bias0A, bias1A, rwA, ccA, shA, hn0);
      xtA += hn0;
      LSTM_STEP_(xtA, w0B, w1B, bias0B, bias1B, rwB, ccB, shB, hn1);
      xtA += hn1;
      LSTM_STEP_(xtB, w0A, w1A, bias0A, bias1A, rwA, ccA, shA, hn0);
      xtB += hn0;
      LSTM_STEP_(xtB, w0B, w1B, bias0B, bias1B, rwB, ccB, shB, hn1);
      xtB += hn1;

      if (low) {
        slot[tau & 1][0][hl] = xtA;
        slot[tau & 1][1][hl] = xtB;
      }
      if (tt == TT_ - 1 && low) {
        out_hT[((size_t)0 * B_ + b) * H_ + hl] = hn0;   // block0 h @ t=S-1
        out_hT[((size_t)1 * B_ + b) * H_ + hl] = hn1;   // block1 h @ t=S-1
        out_cT[((size_t)0 * B_ + b) * H_ + hl] = ccA;
        out_cT[((size_t)1 * B_ + b) * H_ + hl] = ccB;
      }
#pragma unroll
      for (int j = 0; j < 14; ++j) incur[j] = innx[j];
    } else {
      // ---- consumer: blocks 2,3 + head for steps t0, t0+1 ----
      float xtA = slot[tt & 1][0][hl];
      float xtB = slot[tt & 1][1][hl];

      float hn2, hn3;
      LSTM_STEP_(xtA, w0A, w1A, bias0A, bias1A, rwA, ccA, shA, hn2);
      xtA += hn2;
      LSTM_STEP_(xtA, w0B, w1B, bias0B, bias1B, rwB, ccB, shB, hn3);
      xtA += hn3;
      const float p0A = half_reduce_bcast_(xtA * hw0) + hb0;
      const float p1A = half_reduce_bcast_(xtA * hw1) + hb1;

      LSTM_STEP_(xtB, w0A, w1A, bias0A, bias1A, rwA, ccA, shA, hn2);
      xtB += hn2;
      LSTM_STEP_(xtB, w0B, w1B, bias0B, bias1B, rwB, ccB, shB, hn3);
      xtB += hn3;
      const float p0B = half_reduce_bcast_(xtB * hw0) + hb0;
      const float p1B = half_reduce_bcast_(xtB * hw1) + hb1;

      if (lane == 0) {
        const float v0A = copysignf(fminf(ex2_(fabsf(p0A)) - 1.0f, 5.0f),  p0A);
        const float v0B = copysignf(fminf(ex2_(fabsf(p0B)) - 1.0f, 5.0f),  p0B);
        const float v1A = copysignf(fminf(ex2_(fabsf(p1A)) - 1.0f, 10.0f), p1A);
        const float v1B = copysignf(fminf(ex2_(fabsf(p1B)) - 1.0f, 10.0f), p1B);
        *(float2*)&out_y[(size_t)b * S_ + t0]                   = make_float2(v0A, v0B);
        *(float2*)&out_y[(size_t)B_ * S_ + (size_t)b * S_ + t0] = make_float2(v1A, v1B);
      }
      if (tt == TT_ - 1 && low) {
        out_hT[((size_t)2 * B_ + b) * H_ + hl] = hn2;   // block2 h @ t=S-1
        out_hT[((size_t)3 * B_ + b) * H_ + hl] = hn3;   // block3 h @ t=S-1
        out_cT[((size_t)2 * B_ + b) * H_ + hl] = ccA;
        out_cT[((size_t)3 * B_ + b) * H_ + hl] = ccB;
      }
    }
  }
}

extern "C" void kernel_launch(void* const* d_in, const int* in_sizes, int n_in,
                              void* d_out, int out_size, void* d_ws, size_t ws_size,
                              hipStream_t stream) {
  (void)in_sizes; (void)n_in; (void)d_ws; (void)ws_size; (void)out_size;
  garch_noalloca_kernel<<<dim3(B_), dim3(128), 0, stream>>>(
      (const float*)d_in[0],  // obs_sequence [B,S,OBS]
      (const float*)d_in[1],  // prev_actions [B,S,NINS]
      (const float*)d_in[2],  // W_in [H, OBS+NINS]
      (const float*)d_in[3],  // b_in [H]
      (const float*)d_in[4],  // rms_w [NBLK,H]
      (const float*)d_in[5],  // W_ih [NBLK,4H,H]
      (const float*)d_in[6],  // W_hh [NBLK,4H,H]
      (const float*)d_in[7],  // b_ih [NBLK,4H]
      (const float*)d_in[8],  // b_hh [NBLK,4H]
      (const float*)d_in[9],  // head_w [NINS,H]
      (const float*)d_in[10], // head_b [NINS]
      (float*)d_out);
}

// Round 11
// 704.171 us; speedup vs baseline: 2.3288x; 1.0985x over previous
//
#include <hip/hip_runtime.h>

// PolicyNetGARCH: B=1024 S=512 OBS=5 NINS=2 H=32 NBLK=4
// Round 11: MFMA rewrite. WG = 16 batch columns (64 WGs), 4 waves/WG,
// wave k = LSTM block k, R4's skewed pipeline (barrier at loop top,
// predicated roles, parity-double-buffered LDS xt handoff).
// Gates G[128x16] = W_ih @ (rw.*xt) * rinv  +  W_hh @ h + bias via
// v_mfma_f32_16x16x32_f16: 8 M-tiles x 2 = 16 MFMA per block-step; bias
// rides as the C operand of the h-MFMA; rinv (RMSNorm) folds per-column
// after the x-MFMA (diagonal commute).
// KEY: MFMA C/D layout (col=lane&15, row=(lane>>4)*4+reg) == the B-operand
// fragment this lane needs next step (col=lane&15, k=16*ch+4*(lane>>4)+j),
// so h-feedback and xn are pure in-register cvt_pkrtz packs - no LDS, no
// readlane/DPP broadcast apparatus at all.
// Weights prescaled by log2e (2*log2e for tanh/g rows, M-tiles 4,5) so all
// activations are raw v_exp_f32. Input proj = 2 MFMA (K zero-padded).
// Head = per-lane 8-fma + shfl_xor(16/32) reduce + symexp (exp2 domain).

constexpr int B_ = 1024, S_ = 512, OBS_ = 5, NINS_ = 2, H_ = 32, NBLK_ = 4;
constexpr float EPS_ = 1e-6f;
constexpr float LOG2E_ = 1.4426950408889634f;

typedef __fp16 h2 __attribute__((ext_vector_type(2)));
typedef __fp16 h8 __attribute__((ext_vector_type(8)));
typedef float  f4 __attribute__((ext_vector_type(4)));
typedef int    i4 __attribute__((ext_vector_type(4)));

__device__ __forceinline__ float rcp_(float x) { return __builtin_amdgcn_rcpf(x); }
__device__ __forceinline__ float rsq_(float x) { return __builtin_amdgcn_rsqf(x); }
__device__ __forceinline__ float ex2_(float x) { return __builtin_amdgcn_exp2f(x); }
__device__ __forceinline__ h2 pk_(float a, float b) {
  return __builtin_amdgcn_cvt_pkrtz(a, b);
}

// pack 8 f32 (chunk0 = lo, chunk1 = hi) into an f16x8 MFMA operand fragment
__device__ __forceinline__ h8 pk8_(f4 lo, f4 hi) {
  i4 q;
  q[0] = __builtin_bit_cast(int, pk_(lo[0], lo[1]));
  q[1] = __builtin_bit_cast(int, pk_(lo[2], lo[3]));
  q[2] = __builtin_bit_cast(int, pk_(hi[0], hi[1]));
  q[3] = __builtin_bit_cast(int, pk_(hi[2], hi[3]));
  return __builtin_bit_cast(h8, q);
}
__device__ __forceinline__ f4 mfma_(h8 a, h8 b, f4 c) {
  return __builtin_amdgcn_mfma_f32_16x16x32_f16(a, b, c, 0, 0, 0);
}
// sigmoid, input prescaled by log2e
__device__ __forceinline__ f4 sg4_(f4 a) {
  f4 r;
  r[0] = rcp_(1.f + ex2_(-a[0]));
  r[1] = rcp_(1.f + ex2_(-a[1]));
  r[2] = rcp_(1.f + ex2_(-a[2]));
  r[3] = rcp_(1.f + ex2_(-a[3]));
  return r;
}
// tanh, input prescaled by 2*log2e
__device__ __forceinline__ f4 th4_(f4 a) {
  f4 r;
  r[0] = fmaf(2.f, rcp_(1.f + ex2_(-a[0])), -1.f);
  r[1] = fmaf(2.f, rcp_(1.f + ex2_(-a[1])), -1.f);
  r[2] = fmaf(2.f, rcp_(1.f + ex2_(-a[2])), -1.f);
  r[3] = fmaf(2.f, rcp_(1.f + ex2_(-a[3])), -1.f);
  return r;
}
// tanh of linear-domain c
__device__ __forceinline__ f4 thc4_(f4 c) {
  constexpr float M = 2.f * LOG2E_;
  f4 r;
  r[0] = fmaf(2.f, rcp_(1.f + ex2_(-M * c[0])), -1.f);
  r[1] = fmaf(2.f, rcp_(1.f + ex2_(-M * c[1])), -1.f);
  r[2] = fmaf(2.f, rcp_(1.f + ex2_(-M * c[2])), -1.f);
  r[3] = fmaf(2.f, rcp_(1.f + ex2_(-M * c[3])), -1.f);
  return r;
}
__device__ __forceinline__ float dot44_(f4 a, f4 x, f4 b2, f4 y) {
  float s = a[0] * x[0];
  s = fmaf(a[1], x[1], s); s = fmaf(a[2], x[2], s); s = fmaf(a[3], x[3], s);
  s = fmaf(b2[0], y[0], s); s = fmaf(b2[1], y[1], s);
  s = fmaf(b2[2], y[2], s); s = fmaf(b2[3], y[3], s);
  return s;
}

__global__ __launch_bounds__(256, 1) void garch_mfma_kernel(
    const float* __restrict__ obs, const float* __restrict__ prev,
    const float* __restrict__ W_in, const float* __restrict__ b_in,
    const float* __restrict__ rms_w,
    const float* __restrict__ W_ih, const float* __restrict__ W_hh,
    const float* __restrict__ b_ih, const float* __restrict__ b_hh,
    const float* __restrict__ head_w, const float* __restrict__ head_b,
    float* __restrict__ out) {
  const int tid  = threadIdx.x;
  const int k    = tid >> 6;        // wave role == LSTM block
  const int lane = tid & 63;
  const int g    = lane >> 4;       // lane group (k-chunk index)
  const int b    = lane & 15;       // batch column within tile / A-row
  const int bg   = blockIdx.x * 16 + b;

  // xt handoff, C-layout addressed: [stage][parity][bcol][32 rows + pad]
  __shared__ __align__(16) float xslot[3][2][16][36];

  // ---- A-fragments of W_ih / W_hh (8 M-tiles), biases; exp2-prescaled ----
  h8 wxA[8], whA[8];
  f4 biasv[8];
  {
    const size_t wb = (size_t)k * 128 * 32;
#pragma unroll
    for (int mi = 0; mi < 8; ++mi) {
      const float scl = (mi == 4 || mi == 5) ? 2.f * LOG2E_ : LOG2E_;
      const int row = 16 * mi + b;  // A row within tile = lane&15
      const float* px = W_ih + wb + (size_t)row * 32;
      f4 x0 = *(const f4*)(px + 4 * g);
      f4 x1 = *(const f4*)(px + 16 + 4 * g);
      wxA[mi] = pk8_(x0 * scl, x1 * scl);
      const float* ph = W_hh + wb + (size_t)row * 32;
      f4 h0v = *(const f4*)(ph + 4 * g);
      f4 h1v = *(const f4*)(ph + 16 + 4 * g);
      whA[mi] = pk8_(h0v * scl, h1v * scl);
      f4 bv;
#pragma unroll
      for (int r = 0; r < 4; ++r) {
        const int gr = k * 128 + 16 * mi + 4 * g + r;
        bv[r] = (b_ih[gr] + b_hh[gr]) * scl;
      }
      biasv[mi] = bv;
    }
  }
  f4 rw0v, rw1v;
#pragma unroll
  for (int r = 0; r < 4; ++r) {
    rw0v[r] = rms_w[k * 32 + 4 * g + r];
    rw1v[r] = rms_w[k * 32 + 16 + 4 * g + r];
  }

  // ---- role-specific (predicated, R4/R10-proven pattern) ----
  h8 winA0 = {}, winA1 = {};
  f4 bin0v = {}, bin1v = {};
  const float* obs_b = nullptr; const float* prev_b = nullptr;
  float cur0 = 0.f, cur1 = 0.f, cur2 = 0.f, cur3 = 0.f;
  float nx0 = 0.f, nx1 = 0.f, nx2 = 0.f, nx3 = 0.f;
  if (k == 0) {
    f4 lo0, lo1; const f4 z = {};
#pragma unroll
    for (int r = 0; r < 4; ++r) {
      const int kk = 4 * g + r;                 // K index (chunk 0)
      lo0[r] = (kk < 7) ? W_in[(size_t)b * 7 + kk] : 0.f;         // rows 0..15
      lo1[r] = (kk < 7) ? W_in[(size_t)(16 + b) * 7 + kk] : 0.f;  // rows 16..31
    }
    winA0 = pk8_(lo0, z);
    winA1 = pk8_(lo1, z);
#pragma unroll
    for (int r = 0; r < 4; ++r) {
      bin0v[r] = b_in[4 * g + r];
      bin1v[r] = b_in[16 + 4 * g + r];
    }
    obs_b  = obs  + (size_t)bg * S_ * OBS_;
    prev_b = prev + (size_t)bg * S_ * NINS_;
    if (g == 0)      { cur0 = obs_b[0]; cur1 = obs_b[1]; cur2 = obs_b[2]; cur3 = obs_b[3]; }
    else if (g == 1) { cur0 = obs_b[4]; cur1 = prev_b[0]; cur2 = prev_b[1]; cur3 = 0.f; }
  }
  f4 hw00 = {}, hw01 = {}, hw10 = {}, hw11 = {};
  float hb0 = 0.f, hb1 = 0.f;
  if (k == 3) {
#pragma unroll
    for (int r = 0; r < 4; ++r) {
      hw00[r] = head_w[4 * g + r]      * LOG2E_;
      hw01[r] = head_w[16 + 4 * g + r] * LOG2E_;
      hw10[r] = head_w[32 + 4 * g + r] * LOG2E_;
      hw11[r] = head_w[48 + 4 * g + r] * LOG2E_;
    }
    hb0 = head_b[0] * LOG2E_;
    hb1 = head_b[1] * LOG2E_;
  }

  // state (C-layout per lane: rows 4g+r (tile0), 16+4g+r (tile1), col b)
  f4 c0 = {}, c1 = {}, hv0 = {}, hv1 = {};

  float* out_y  = out;                                // [2][B][S]
  float* out_hT = out + (size_t)NINS_ * B_ * S_;      // [4][B][H]
  float* out_cT = out_hT + (size_t)NBLK_ * B_ * H_;   // [4][B][H]

  for (int tau = 0; tau < S_ + NBLK_ - 1; ++tau) {
    __syncthreads();
    const int t = tau - k;            // wave-uniform
    if (t < 0 || t >= S_) continue;
    const int wp = tau & 1, rp = (tau + 1) & 1;

    // ---- 1. xt tiles (C layout) ----
    f4 xt0, xt1;
    if (k == 0) {
      if (t + 1 < S_) {               // prefetch next tick's inputs
        const float* o2 = obs_b + (size_t)(t + 1) * OBS_;
        if (g == 0)      { nx0 = o2[0]; nx1 = o2[1]; nx2 = o2[2]; nx3 = o2[3]; }
        else if (g == 1) { nx0 = o2[4]; nx1 = prev_b[2 * (t + 1)]; nx2 = prev_b[2 * (t + 1) + 1]; nx3 = 0.f; }
      }
      const f4 lo = { cur0, cur1, cur2, cur3 };  // g>=2 lanes: zeros
      const f4 z = {};
      const h8 binp = pk8_(lo, z);
      xt0 = mfma_(winA0, binp, bin0v);
      xt1 = mfma_(winA1, binp, bin1v);
    } else {
      xt0 = *(const f4*)&xslot[k - 1][rp][b][4 * g];
      xt1 = *(const f4*)&xslot[k - 1][rp][b][16 + 4 * g];
    }

    // ---- 2. RMS (per batch column; rows live across lane groups) ----
    float ss = dot44_(xt0, xt0, xt1, xt1);
    ss += __shfl_xor(ss, 16);
    ss += __shfl_xor(ss, 32);
    const float rinv = rsq_(ss * (1.0f / 32.0f) + EPS_);

    // ---- 3. B operands: in-register (C layout == B fragment layout) ----
    const h8 bx = pk8_(xt0 * rw0v, xt1 * rw1v);   // rinv folded post-MFMA
    const h8 bh = pk8_(hv0, hv1);

    // ---- 4. gates: 16 MFMA; bias rides as C of the h-part ----
    const f4 z4 = {};
    f4 gi0, gi1, gf0, gf1, gg0, gg1, go0, go1;
    {
      f4 ax, ah;
      ax = mfma_(wxA[0], bx, z4); ah = mfma_(whA[0], bh, biasv[0]); gi0 = ax * rinv + ah;
      ax = mfma_(wxA[1], bx, z4); ah = mfma_(whA[1], bh, biasv[1]); gi1 = ax * rinv + ah;
      ax = mfma_(wxA[2], bx, z4); ah = mfma_(whA[2], bh, biasv[2]); gf0 = ax * rinv + ah;
      ax = mfma_(wxA[3], bx, z4); ah = mfma_(whA[3], bh, biasv[3]); gf1 = ax * rinv + ah;
      ax = mfma_(wxA[4], bx, z4); ah = mfma_(whA[4], bh, biasv[4]); gg0 = ax * rinv + ah;
      ax = mfma_(wxA[5], bx, z4); ah = mfma_(whA[5], bh, biasv[5]); gg1 = ax * rinv + ah;
      ax = mfma_(wxA[6], bx, z4); ah = mfma_(whA[6], bh, biasv[6]); go0 = ax * rinv + ah;
      ax = mfma_(wxA[7], bx, z4); ah = mfma_(whA[7], bh, biasv[7]); go1 = ax * rinv + ah;
    }

    // ---- 5. activations + state update (all lane-local) ----
    const f4 si0 = sg4_(gi0), si1 = sg4_(gi1);
    const f4 sf0 = sg4_(gf0), sf1 = sg4_(gf1);
    const f4 tg0 = th4_(gg0), tg1 = th4_(gg1);
    const f4 so0 = sg4_(go0), so1 = sg4_(go1);
    c0 = sf0 * c0 + si0 * tg0;
    c1 = sf1 * c1 + si1 * tg1;
    const f4 tc0 = thc4_(c0), tc1 = thc4_(c1);
    hv0 = so0 * tc0;
    hv1 = so1 * tc1;
    xt0 += hv0;
    xt1 += hv1;

    // ---- 6. handoff or head ----
    if (k < 3) {
      *(f4*)&xslot[k][wp][b][4 * g]      = xt0;
      *(f4*)&xslot[k][wp][b][16 + 4 * g] = xt1;
    } else {
      float p0 = dot44_(hw00, xt0, hw01, xt1);
      float p1 = dot44_(hw10, xt0, hw11, xt1);
      p0 += __shfl_xor(p0, 16); p0 += __shfl_xor(p0, 32);
      p1 += __shfl_xor(p1, 16); p1 += __shfl_xor(p1, 32);
      p0 += hb0; p1 += hb1;
      if (lane < 16) {
        const float v0 = copysignf(fminf(ex2_(fabsf(p0)) - 1.f, 5.f),  p0);
        const float v1 = copysignf(fminf(ex2_(fabsf(p1)) - 1.f, 10.f), p1);
        out_y[(size_t)bg * S_ + t]                    = v0;
        out_y[(size_t)B_ * S_ + (size_t)bg * S_ + t]  = v1;
      }
    }

    // ---- 7. final states ----
    if (t == S_ - 1) {
      float* hp = out_hT + ((size_t)k * B_ + bg) * H_;
      float* cp = out_cT + ((size_t)k * B_ + bg) * H_;
#pragma unroll
      for (int r = 0; r < 4; ++r) {
        hp[4 * g + r]      = hv0[r];
        hp[16 + 4 * g + r] = hv1[r];
        cp[4 * g + r]      = c0[r];
        cp[16 + 4 * g + r] = c1[r];
      }
    }

    if (k == 0) { cur0 = nx0; cur1 = nx1; cur2 = nx2; cur3 = nx3; }
  }
}

extern "C" void kernel_launch(void* const* d_in, const int* in_sizes, int n_in,
                              void* d_out, int out_size, void* d_ws, size_t ws_size,
                              hipStream_t stream) {
  (void)in_sizes; (void)n_in; (void)d_ws; (void)ws_size; (void)out_size;
  garch_mfma_kernel<<<dim3(B_ / 16), dim3(256), 0, stream>>>(
      (const float*)d_in[0],  // obs_sequence [B,S,OBS]
      (const float*)d_in[1],  // prev_actions [B,S,NINS]
      (const float*)d_in[2],  // W_in [H, OBS+NINS]
      (const float*)d_in[3],  // b_in [H]
      (const float*)d_in[4],  // rms_w [NBLK,H]
      (const float*)d_in[5],  // W_ih [NBLK,4H,H]
      (const float*)d_in[6],  // W_hh [NBLK,4H,H]
      (const float*)d_in[7],  // b_ih [NBLK,4H]
      (const float*)d_in[8],  // b_hh [NBLK,4H]
      (const float*)d_in[9],  // head_w [NINS,H]
      (const float*)d_in[10], // head_b [NINS]
      (float*)d_out);
}